// Round 5
// baseline (1283.852 us; speedup 1.0000x reference)
//
#include <hip/hip_runtime.h>
#include <cstdint>
#include <cstddef>

#define BB 256
#define TT 250
#define DIN 700
#define H1 256
#define H2 256
#define DOUT 20
#define BJ0 0.01f
#define BETAC 1.8f

typedef float    f32x4 __attribute__((ext_vector_type(4)));
typedef _Float16 f16x4 __attribute__((ext_vector_type(4)));

// ---------------------------------------------------------------------------
// Workspace layout.
// FP16 region (element offsets in halves, from ws base):
//   hT1  [701*256] @ 0        (row 700 = zeros)   feedforward
//   hT11 [257*256] @ 179456   (row 256 = zeros)
//   hT12 [257*256] @ 245248
//   hT22 [257*256] @ 311040
//   end 376832 halves = 753664 bytes
// FP32 region (float offsets from ws base):
//   wT2o [257*20]  @ f188416  (row 256 = zeros)
//   Xp   [250*256*256] @ f193556  (byte 774224, 16B aligned)
// total ~66.3 MB
// ---------------------------------------------------------------------------
#define HOFF_T11 179456
#define HOFF_T12 245248
#define HOFF_T22 311040
#define FOFF_W2O 188416
#define FOFF_XP  193556
#define DELTA22  131584          // hT22 - hT11 in half elements
#define DUMMY1   65536           // 256<<8: zero row, region 1
#define DUMMY2   (65536 + DELTA22)

__global__ void transpose_all_k(const float* __restrict__ w_i2h1,
                                const float* __restrict__ w_h12h1,
                                const float* __restrict__ w_h12h2,
                                const float* __restrict__ w_h22h2,
                                const float* __restrict__ w_h2o,
                                _Float16* __restrict__ hws,
                                float* __restrict__ fws) {
    int i = blockIdx.x * blockDim.x + threadIdx.x;
    if (i < 179456) { int d = i >> 8, h = i & 255;
        hws[i] = (_Float16)((d < DIN) ? w_i2h1[h * DIN + d] : 0.f); return; }
    i -= 179456;
    if (i < 65792) { int d = i >> 8, h = i & 255;
        hws[HOFF_T11 + i] = (_Float16)((d < H1) ? w_h12h1[h * H1 + d] : 0.f); return; }
    i -= 65792;
    if (i < 65792) { int d = i >> 8, h = i & 255;
        hws[HOFF_T12 + i] = (_Float16)((d < H1) ? w_h12h2[h * H1 + d] : 0.f); return; }
    i -= 65792;
    if (i < 65792) { int d = i >> 8, h = i & 255;
        hws[HOFF_T22 + i] = (_Float16)((d < H2) ? w_h22h2[h * H2 + d] : 0.f); return; }
    i -= 65792;
    if (i < 5140)  { int j = i / 20, h = i % 20;
        fws[FOFF_W2O + i] = (j < H2) ? w_h2o[h * H2 + j] : 0.f; return; }
}

// ---------------------------------------------------------------------------
// Xp[t][b][h] = b_h1[h] + sum_{d active} hT1[d*256 + h]   (fp16 table)
// One wave per (b,t); lane covers h=4l..4l+3. List padded to multiple of 8.
// ---------------------------------------------------------------------------
__global__ __launch_bounds__(256) void xproj_k(const float* __restrict__ x,
                                               const _Float16* __restrict__ hT1,
                                               const float* __restrict__ b_h1,
                                               float* __restrict__ Xp) {
    const int lane = threadIdx.x & 63;
    const int wv   = threadIdx.x >> 6;
    const int bt   = blockIdx.x * 4 + wv;   // grid = T*B/4 = 16000
    const int b    = bt & (BB - 1);
    const int t    = bt >> 8;

    __shared__ __align__(16) int lst[4][712];

    const float* xrow = x + ((size_t)b * TT + t) * DIN;
    int cnt = 0;
    for (int c = 0; c < 11; ++c) {
        int d = c * 64 + lane;
        bool p = false;
        if (d < DIN) p = (__builtin_nontemporal_load(xrow + d) != 0.0f);
        unsigned long long m = __ballot(p ? 1 : 0);
        if (p) {
            int pos = cnt + __popcll(m & ((1ull << lane) - 1ull));
            lst[wv][pos] = d;
        }
        cnt += __popcll(m);
    }
    int cntp = (cnt + 7) & ~7;
    if (lane < cntp - cnt) lst[wv][cnt + lane] = DIN;   // zero row pad
    __syncthreads();

    f32x4 acc0 = *(const f32x4*)(b_h1 + lane * 4);
    f32x4 acc1 = {0.f, 0.f, 0.f, 0.f};
    const int lo = lane * 4;
    for (int k = 0; k < cntp; k += 8) {
        int4 ja = *(const int4*)&lst[wv][k];
        int4 jb = *(const int4*)&lst[wv][k + 4];
        f16x4 w0 = *(const f16x4*)(hT1 + ((size_t)ja.x << 8) + lo);
        f16x4 w1 = *(const f16x4*)(hT1 + ((size_t)ja.y << 8) + lo);
        f16x4 w2 = *(const f16x4*)(hT1 + ((size_t)ja.z << 8) + lo);
        f16x4 w3 = *(const f16x4*)(hT1 + ((size_t)ja.w << 8) + lo);
        f16x4 w4 = *(const f16x4*)(hT1 + ((size_t)jb.x << 8) + lo);
        f16x4 w5 = *(const f16x4*)(hT1 + ((size_t)jb.y << 8) + lo);
        f16x4 w6 = *(const f16x4*)(hT1 + ((size_t)jb.z << 8) + lo);
        f16x4 w7 = *(const f16x4*)(hT1 + ((size_t)jb.w << 8) + lo);
        acc0 += (__builtin_convertvector(w0, f32x4) + __builtin_convertvector(w1, f32x4))
              + (__builtin_convertvector(w2, f32x4) + __builtin_convertvector(w3, f32x4));
        acc1 += (__builtin_convertvector(w4, f32x4) + __builtin_convertvector(w5, f32x4))
              + (__builtin_convertvector(w6, f32x4) + __builtin_convertvector(w7, f32x4));
    }
    acc0 += acc1;
    __builtin_nontemporal_store(acc0, (f32x4*)(Xp + ((size_t)t * BB + b) * H1 + lo));
}

// ---------------------------------------------------------------------------
// 32 fp16 gathered values from entry offsets lstC[g..g+32) against base W.
// Loads emitted before sums (all 32 in flight).
// ---------------------------------------------------------------------------
__device__ __forceinline__ void load32(const _Float16* __restrict__ W,
                                       const int* L, int g, int h,
                                       _Float16 v[32]) {
    #pragma unroll
    for (int i = 0; i < 32; i += 4) {
        int4 a = *(const int4*)(L + g + i);
        v[i + 0] = W[a.x + h];
        v[i + 1] = W[a.y + h];
        v[i + 2] = W[a.z + h];
        v[i + 3] = W[a.w + h];
    }
}

__device__ __forceinline__ float sum32(const _Float16 v[32]) {
    float s0 = 0.f, s1 = 0.f, s2 = 0.f, s3 = 0.f;
    #pragma unroll
    for (int i = 0; i < 32; i += 4) {
        s0 += (float)v[i + 0];
        s1 += (float)v[i + 1];
        s2 += (float)v[i + 2];
        s3 += (float)v[i + 3];
    }
    return (s0 + s1) + (s2 + s3);
}

// 32 fp32 output-weight values for region-2 entries (e = j<<8 + DELTA22).
__device__ __forceinline__ float gather32o(const float* __restrict__ W,
                                           const int* L, int g, int h) {
    float s0 = 0.f, s1 = 0.f, s2 = 0.f, s3 = 0.f;
    #pragma unroll
    for (int i = 0; i < 32; i += 4) {
        int4 a = *(const int4*)(L + g + i);
        int j0 = (a.x - DELTA22) >> 8, j1 = (a.y - DELTA22) >> 8;
        int j2 = (a.z - DELTA22) >> 8, j3 = (a.w - DELTA22) >> 8;
        s0 += W[j0 * DOUT + h];
        s1 += W[j1 * DOUT + h];
        s2 += W[j2 * DOUT + h];
        s3 += W[j3 * DOUT + h];
    }
    return (s0 + s1) + (s2 + s3);
}

// ---------------------------------------------------------------------------
// Recurrent loop: one 256-thread block per batch element, thread h = neuron.
// Combined flat list lstC: [0..n1p) = layer1 entries (j<<8),
// [n1p..n1p+n2p) = layer2 entries (j<<8 + DELTA22). Pad to 32 w/ zero rows.
// P1 gathers hT11 (region1) + hT22 (region2, via baked offset) + wT2o (wave0)
// in ONE loop, 64 loads in flight per iteration. 4 barriers/step.
// ---------------------------------------------------------------------------
__global__ __launch_bounds__(256) void rec_k(
    const float* __restrict__ Xp,
    const _Float16* __restrict__ hT11,          // hT12 = hT11 + 65792
    const float* __restrict__ wT2o,
    const float* __restrict__ b_h2, const float* __restrict__ b_o,
    const float* __restrict__ tau_adp_h1, const float* __restrict__ tau_adp_h2,
    const float* __restrict__ tau_m_h1, const float* __restrict__ tau_m_h2,
    const float* __restrict__ tau_m_o,
    float* __restrict__ out) {
    const int h    = threadIdx.x;
    const int lane = h & 63;
    const int wv   = h >> 6;
    const int b    = blockIdx.x;
    const _Float16* __restrict__ hT12 = hT11 + 65792;

    __shared__ __align__(16) int lstC[544];
    __shared__ unsigned long long wmask[4];
    __shared__ float smo[DOUT];

    const float alpha1 = expf(-1.0f / tau_m_h1[h]);
    const float ro1    = expf(-1.0f / tau_adp_h1[h]);
    const float alpha2 = expf(-1.0f / tau_m_h2[h]);
    const float ro2    = expf(-1.0f / tau_adp_h2[h]);
    const float bh2v   = b_h2[h];
    float alpo = 0.f, bov = 0.f;
    if (h < DOUT) { alpo = expf(-1.0f / tau_m_o[h]); bov = b_o[h]; }

    float mem1 = 0.f, spk1 = 0.f, bb1v = BJ0;
    float mem2 = 0.f, spk2 = 0.f, bb2v = BJ0;
    float memo = 0.f, accs = 0.f;
    int n1p = 0, n2p = 0;

    float xp_cur = __builtin_nontemporal_load(Xp + ((size_t)b) * H1 + h);  // t=0

    for (int t = 0; t < TT; ++t) {
        // prefetch next step's Xp — a whole step of latency to cover it
        float xp_nxt = 0.f;
        if (t + 1 < TT)
            xp_nxt = __builtin_nontemporal_load(Xp + ((size_t)(t + 1) * BB + b) * H1 + h);

        // ---- P1: combined gather over lstC (hT11 | hT22 | wT2o) ----
        float r1 = 0.f, r2 = 0.f, ro = 0.f;
        const bool doo = (h < DOUT) && (t > 0);
        const int kmax = n1p + n2p;
        int g = 0;
        for (; g + 64 <= kmax; g += 64) {
            _Float16 A[32], Bv[32];
            load32(hT11, lstC, g,      h, A);
            load32(hT11, lstC, g + 32, h, Bv);
            float sA = sum32(A), sB = sum32(Bv);
            if (g      < n1p) r1 += sA; else r2 += sA;
            if (g + 32 < n1p) r1 += sB; else r2 += sB;
            if (doo) {
                if (g      >= n1p) ro += gather32o(wT2o, lstC, g,      h);
                if (g + 32 >= n1p) ro += gather32o(wT2o, lstC, g + 32, h);
            }
        }
        if (g < kmax) {
            _Float16 A[32];
            load32(hT11, lstC, g, h, A);
            float sA = sum32(A);
            if (g < n1p) r1 += sA;
            else { r2 += sA; if (doo) ro += gather32o(wT2o, lstC, g, h); }
        }

        // ---- U1: layer-1 update; output memo for step t-1 ----
        bb1v = ro1 * bb1v + BETAC * (1.f - ro1) * spk1;
        mem1 = mem1 * alpha1 - bb1v * spk1 + (1.f - alpha1) * (xp_cur + r1);
        float ns1 = (mem1 - bb1v - BJ0) > 0.f ? 1.f : 0.f;
        spk1 = ns1;
        unsigned long long m1 = __ballot(ns1 != 0.f ? 1 : 0);
        if (lane == 0) wmask[wv] = m1;
        if (doo) {
            memo = memo * alpo + (1.f - alpo) * (bov + ro);
            smo[h] = memo;
        }
        __syncthreads();                               // B1

        // ---- P2b: build region-1 of lstC (raw j<<8); softmax for t-1 ----
        {
            int pos = __popcll(m1 & ((1ull << lane) - 1ull));
            int tot = 0;
            for (int w = 0; w < 4; ++w) {
                unsigned long long mw = wmask[w];
                if (w < wv) pos += __popcll(mw);
                tot += __popcll(mw);
            }
            if (ns1 != 0.f) lstC[pos] = h << 8;
            int np = (tot + 31) & ~31;
            if (h < np - tot) lstC[tot + h] = DUMMY1;
            n1p = np;
        }
        if (doo) {
            float mx = smo[0];
            for (int i = 1; i < DOUT; ++i) mx = fmaxf(mx, smo[i]);
            float s = 0.f;
            for (int i = 0; i < DOUT; ++i) s += expf(smo[i] - mx);
            accs += expf(memo - mx) / s;
        }
        __syncthreads();                               // B2

        // ---- P3: gather hT12 over new region-1 ----
        float r3 = 0.f;
        g = 0;
        for (; g + 64 <= n1p; g += 64) {
            _Float16 A[32], Bv[32];
            load32(hT12, lstC, g,      h, A);
            load32(hT12, lstC, g + 32, h, Bv);
            r3 += sum32(A) + sum32(Bv);
        }
        if (g < n1p) {
            _Float16 A[32];
            load32(hT12, lstC, g, h, A);
            r3 += sum32(A);
        }

        // ---- U2: layer-2 update ----
        bb2v = ro2 * bb2v + BETAC * (1.f - ro2) * spk2;
        mem2 = mem2 * alpha2 - bb2v * spk2 + (1.f - alpha2) * (bh2v + r2 + r3);
        float ns2 = (mem2 - bb2v - BJ0) > 0.f ? 1.f : 0.f;
        spk2 = ns2;
        unsigned long long m2 = __ballot(ns2 != 0.f ? 1 : 0);
        if (lane == 0) wmask[wv] = m2;
        __syncthreads();                               // B3

        // ---- P4b: build region-2 of lstC (j<<8 + DELTA22) ----
        {
            int pos = __popcll(m2 & ((1ull << lane) - 1ull));
            int tot = 0;
            for (int w = 0; w < 4; ++w) {
                unsigned long long mw = wmask[w];
                if (w < wv) pos += __popcll(mw);
                tot += __popcll(mw);
            }
            if (ns2 != 0.f) lstC[n1p + pos] = (h << 8) + DELTA22;
            int np = (tot + 31) & ~31;
            if (h < np - tot) lstC[n1p + tot + h] = DUMMY2;
            n2p = np;
        }
        __syncthreads();                               // B4

        xp_cur = xp_nxt;
    }

    // ---- Epilogue: output + softmax for final timestep ----
    if (h < DOUT) {
        float ro = 0.f;
        for (int g2 = n1p; g2 < n1p + n2p; g2 += 32)
            ro += gather32o(wT2o, lstC, g2, h);
        memo = memo * alpo + (1.f - alpo) * (bov + ro);
        smo[h] = memo;
    }
    __syncthreads();
    if (h < DOUT) {
        float mx = smo[0];
        for (int i = 1; i < DOUT; ++i) mx = fmaxf(mx, smo[i]);
        float s = 0.f;
        for (int i = 0; i < DOUT; ++i) s += expf(smo[i] - mx);
        accs += expf(memo - mx) / s;
        out[b * DOUT + h] = accs;
    }
}

extern "C" void kernel_launch(void* const* d_in, const int* in_sizes, int n_in,
                              void* d_out, int out_size, void* d_ws, size_t ws_size,
                              hipStream_t stream) {
    const float* x          = (const float*)d_in[0];
    const float* w_i2h1     = (const float*)d_in[1];
    const float* w_h12h1    = (const float*)d_in[2];
    const float* w_h12h2    = (const float*)d_in[3];
    const float* w_h22h2    = (const float*)d_in[4];
    const float* w_h2o      = (const float*)d_in[5];
    const float* b_h1       = (const float*)d_in[6];
    const float* b_h2       = (const float*)d_in[7];
    const float* b_o        = (const float*)d_in[8];
    const float* tau_adp_h1 = (const float*)d_in[9];
    const float* tau_adp_h2 = (const float*)d_in[10];
    const float* tau_m_h1   = (const float*)d_in[11];
    const float* tau_m_h2   = (const float*)d_in[12];
    const float* tau_m_o    = (const float*)d_in[13];

    _Float16* hws = (_Float16*)d_ws;
    float*    fws = (float*)d_ws;
    const _Float16* hT1  = hws;
    const _Float16* hT11 = hws + HOFF_T11;
    float* wT2o = fws + FOFF_W2O;
    float* Xp   = fws + FOFF_XP;

    transpose_all_k<<<(381972 + 255) / 256, 256, 0, stream>>>(
        w_i2h1, w_h12h1, w_h12h2, w_h22h2, w_h2o, hws, fws);

    xproj_k<<<(TT * BB) / 4, 256, 0, stream>>>(x, hT1, b_h1, Xp);

    rec_k<<<BB, 256, 0, stream>>>(Xp, hT11, wT2o,
                                  b_h2, b_o, tau_adp_h1, tau_adp_h2,
                                  tau_m_h1, tau_m_h2, tau_m_o,
                                  (float*)d_out);
}